// Round 2
// baseline (103.233 us; speedup 1.0000x reference)
//
#include <hip/hip_runtime.h>
#include <stdint.h>

// Problem dims (fixed by reference setup_inputs)
#define NNODES 20000
#define NSRC   2048
#define DIN    128

typedef short s16x8 __attribute__((ext_vector_type(8)));
typedef unsigned short u16x8 __attribute__((ext_vector_type(8)));
typedef float f32x4 __attribute__((ext_vector_type(4)));

// round-to-nearest-even f32 -> bf16 bits
static __device__ __forceinline__ unsigned short f2bf(float f) {
  union { float f; unsigned int u; } v; v.f = f;
  unsigned int r = v.u + 0x7FFFu + ((v.u >> 16) & 1u);
  return (unsigned short)(r >> 16);
}

// load 8 consecutive f32 (32B-aligned) and convert to bf16x8 (as short8)
static __device__ __forceinline__ s16x8 load_cvt8(const float* __restrict__ p) {
  const float4 f0 = *reinterpret_cast<const float4*>(p);
  const float4 f1 = *reinterpret_cast<const float4*>(p + 4);
  s16x8 r;
  r[0] = (short)f2bf(f0.x); r[1] = (short)f2bf(f0.y);
  r[2] = (short)f2bf(f0.z); r[3] = (short)f2bf(f0.w);
  r[4] = (short)f2bf(f1.x); r[5] = (short)f2bf(f1.y);
  r[6] = (short)f2bf(f1.z); r[7] = (short)f2bf(f1.w);
  return r;
}

// ---------------------------------------------------------------------------
// Kernel 1: supportT[j][s] = bf16( sum_k x[src_idx[s]][k] * W[k][j] )
// grid = NSRC/8 blocks of 128 threads; each block does 8 sources.
// ---------------------------------------------------------------------------
__global__ __launch_bounds__(128) void support_kernel(
    const float* __restrict__ x, const float* __restrict__ W,
    const int* __restrict__ src_idx, unsigned short* __restrict__ supT) {
  __shared__ float xrows[8][DIN];
  const int j = threadIdx.x;           // feature 0..127
  const int s0 = blockIdx.x * 8;       // first source of this block
#pragma unroll
  for (int i = 0; i < 8; ++i) {
    const int src = src_idx[s0 + i];
    xrows[i][j] = x[(size_t)src * DIN + j];
  }
  __syncthreads();
  float acc[8];
#pragma unroll
  for (int i = 0; i < 8; ++i) acc[i] = 0.f;
  for (int k = 0; k < DIN; ++k) {
    const float w = W[(size_t)k * DIN + j];   // coalesced across threads
#pragma unroll
    for (int i = 0; i < 8; ++i) acc[i] += xrows[i][k] * w;  // LDS broadcast
  }
  u16x8 o;
#pragma unroll
  for (int i = 0; i < 8; ++i) o[i] = f2bf(acc[i]);
  *reinterpret_cast<u16x8*>(&supT[(size_t)j * NSRC + s0]) = o;  // 16B store
}

// ---------------------------------------------------------------------------
// Kernel 2: out = LeakyReLU(A @ support) @ dense0_w^T
// 1 wave per block, 32 output rows per wave (two 16-row MFMA tiles), N=128.
// grid = NNODES/32 = 625 blocks of 64 threads.
// MFMA 16x16x32 bf16 layouts:
//   A-frag: lane l holds A[l&15][(l>>4)*8 + e], e=0..7
//   B-frag: lane l holds B[(l>>4)*8 + e][l&15]
//   C/D   : lane l holds C[(l>>4)*4 + r][l&15]   (verified, learn_hip m89/m91)
// ---------------------------------------------------------------------------
__global__ __launch_bounds__(64) void fused_gcn_kernel(
    const float* __restrict__ A,            // [NNODES][NSRC] f32
    const unsigned short* __restrict__ supT,// [DIN][NSRC] bf16 bits
    const float* __restrict__ Wd,           // dense0_w [DIN][DIN] f32
    float* __restrict__ out) {              // [NNODES][DIN] f32
  const int lane = threadIdx.x & 63;
  const int r16 = lane & 15;
  const int g = lane >> 4;                  // 0..3
  const int rowBase = blockIdx.x * 32;

  // act tile for the second GEMM; pad row to 136 bf16 so 16B LDS loads stay
  // 16B-aligned (136*2 = 272 = 17*16).
  __shared__ unsigned short act[32][136];

  f32x4 acc[2][8];
#pragma unroll
  for (int m = 0; m < 2; ++m)
#pragma unroll
    for (int n = 0; n < 8; ++n) acc[m][n] = (f32x4){0.f, 0.f, 0.f, 0.f};

  const float* aRow0 = A + (size_t)(rowBase + r16) * NSRC;      // m=0 rows
  const float* aRow1 = aRow0 + (size_t)16 * NSRC;               // m=1 rows
  const unsigned short* bBase = supT + (size_t)r16 * NSRC + g * 8;

  for (int kk = 0; kk < NSRC / 32; ++kk) {
    const int k = kk * 32 + g * 8;
    const s16x8 a0 = load_cvt8(aRow0 + k);   // HBM stream + cvt
    const s16x8 a1 = load_cvt8(aRow1 + k);
#pragma unroll
    for (int n = 0; n < 8; ++n) {
      const s16x8 b = *reinterpret_cast<const s16x8*>(
          bBase + (size_t)n * 16 * NSRC + kk * 32);   // L2-resident, 16B
      acc[0][n] = __builtin_amdgcn_mfma_f32_16x16x32_bf16(a0, b, acc[0][n], 0, 0, 0);
      acc[1][n] = __builtin_amdgcn_mfma_f32_16x16x32_bf16(a1, b, acc[1][n], 0, 0, 0);
    }
  }

  // LeakyReLU + spill act tile (bf16) to LDS in row-major for re-fragmenting
#pragma unroll
  for (int m = 0; m < 2; ++m)
#pragma unroll
    for (int n = 0; n < 8; ++n)
#pragma unroll
      for (int r = 0; r < 4; ++r) {
        float v = acc[m][n][r];
        v = (v >= 0.f) ? v : 0.01f * v;
        act[m * 16 + g * 4 + r][n * 16 + r16] = f2bf(v);
      }
  __syncthreads();

  // Second GEMM: out[i][j] = sum_k act[i][k] * Wd[j][k]
  // B2-frag: lane l holds B2[k0+8g+e][16n+r16] = Wd[16n+r16][k0+8g+e] -> row-contig
  f32x4 acc2[2][8];
#pragma unroll
  for (int m = 0; m < 2; ++m)
#pragma unroll
    for (int n = 0; n < 8; ++n) acc2[m][n] = (f32x4){0.f, 0.f, 0.f, 0.f};

#pragma unroll
  for (int k2 = 0; k2 < 4; ++k2) {
    const int k = k2 * 32 + g * 8;
    const s16x8 a20 = *reinterpret_cast<const s16x8*>(&act[r16][k]);
    const s16x8 a21 = *reinterpret_cast<const s16x8*>(&act[16 + r16][k]);
#pragma unroll
    for (int n = 0; n < 8; ++n) {
      const s16x8 b2 = load_cvt8(Wd + (size_t)(n * 16 + r16) * DIN + k);
      acc2[0][n] = __builtin_amdgcn_mfma_f32_16x16x32_bf16(a20, b2, acc2[0][n], 0, 0, 0);
      acc2[1][n] = __builtin_amdgcn_mfma_f32_16x16x32_bf16(a21, b2, acc2[1][n], 0, 0, 0);
    }
  }

  // Store f32 output (C/D layout -> 16 consecutive floats per 16-lane group)
#pragma unroll
  for (int m = 0; m < 2; ++m)
#pragma unroll
    for (int n = 0; n < 8; ++n)
#pragma unroll
      for (int r = 0; r < 4; ++r)
        out[(size_t)(rowBase + m * 16 + g * 4 + r) * DIN + n * 16 + r16] =
            acc2[m][n][r];
}

// ---------------------------------------------------------------------------
extern "C" void kernel_launch(void* const* d_in, const int* in_sizes, int n_in,
                              void* d_out, int out_size, void* d_ws, size_t ws_size,
                              hipStream_t stream) {
  const float* x   = (const float*)d_in[0];   // [20000][128]
  const float* A   = (const float*)d_in[1];   // [20000][2048]
  const float* W   = (const float*)d_in[2];   // [128][128]
  const float* Wd  = (const float*)d_in[3];   // [128][128]
  const int*   src = (const int*)d_in[4];     // [2048] (int canonicalized to i32)
  float* out = (float*)d_out;

  unsigned short* supT = (unsigned short*)d_ws;  // needs 128*2048*2 = 512 KB

  support_kernel<<<NSRC / 8, 128, 0, stream>>>(x, W, src, supT);
  fused_gcn_kernel<<<NNODES / 32, 64, 0, stream>>>(A, supT, Wd, out);
}

// Round 4
// 97.723 us; speedup vs baseline: 1.0564x; 1.0564x over previous
//
#include <hip/hip_runtime.h>
#include <stdint.h>

// Problem dims (fixed by reference setup_inputs)
#define NNODES 20000
#define NSRC   2048
#define DIN    128

typedef short s16x8 __attribute__((ext_vector_type(8)));
typedef unsigned short u16x8 __attribute__((ext_vector_type(8)));
typedef float f32x4 __attribute__((ext_vector_type(4)));

// round-to-nearest-even f32 -> bf16 bits
static __device__ __forceinline__ unsigned short f2bf(float f) {
  union { float f; unsigned int u; } v; v.f = f;
  unsigned int r = v.u + 0x7FFFu + ((v.u >> 16) & 1u);
  return (unsigned short)(r >> 16);
}

static __device__ __forceinline__ s16x8 pack8(float4 a, float4 b) {
  s16x8 r;
  r[0] = (short)f2bf(a.x); r[1] = (short)f2bf(a.y);
  r[2] = (short)f2bf(a.z); r[3] = (short)f2bf(a.w);
  r[4] = (short)f2bf(b.x); r[5] = (short)f2bf(b.y);
  r[6] = (short)f2bf(b.z); r[7] = (short)f2bf(b.w);
  return r;
}

static __device__ __forceinline__ s16x8 load_cvt8(const float* __restrict__ p) {
  return pack8(*reinterpret_cast<const float4*>(p),
               *reinterpret_cast<const float4*>(p + 4));
}

#define GLL16(g, l)                                                          \
  __builtin_amdgcn_global_load_lds(                                          \
      (const __attribute__((address_space(1))) void*)(g),                    \
      (__attribute__((address_space(3))) void*)(l), 16, 0, 0)

// ---------------------------------------------------------------------------
// Kernel 1: supportT[j][s] = bf16( sum_k x[src_idx[s]][k] * W[k][j] )
// ---------------------------------------------------------------------------
__global__ __launch_bounds__(128) void support_kernel(
    const float* __restrict__ x, const float* __restrict__ W,
    const int* __restrict__ src_idx, unsigned short* __restrict__ supT) {
  __shared__ float xrows[8][DIN];
  const int j = threadIdx.x;
  const int s0 = blockIdx.x * 8;
#pragma unroll
  for (int i = 0; i < 8; ++i) {
    const int src = src_idx[s0 + i];
    xrows[i][j] = x[(size_t)src * DIN + j];
  }
  __syncthreads();
  float acc[8];
#pragma unroll
  for (int i = 0; i < 8; ++i) acc[i] = 0.f;
  for (int k = 0; k < DIN; ++k) {
    const float w = W[(size_t)k * DIN + j];
#pragma unroll
    for (int i = 0; i < 8; ++i) acc[i] += xrows[i][k] * w;
  }
  u16x8 o;
#pragma unroll
  for (int i = 0; i < 8; ++i) o[i] = f2bf(acc[i]);
  *reinterpret_cast<u16x8*>(&supT[(size_t)j * NSRC + s0]) = o;
}

// ---------------------------------------------------------------------------
// Kernel 2: out = LeakyReLU(A @ support) @ dense0_w^T
// 1 wave/block, 32 rows/block, grid 625. K-loop fully DMA-staged:
//   per chunk (BK=64): A[32][64] f32 (8 gll, 8KB) + B[128][64] bf16 (16 gll,
//   16KB), double-buffered, counted s_waitcnt vmcnt(24) — 24KB/wave in flight.
// LDS XOR swizzle (16B slots): slot' = slot ^ (row & mask), with the inverse
// swizzle applied to the per-lane GLOBAL source address (gll dest must stay
// linear: base + lane*16). Reads apply the same XOR — involution.
// MFMA 16x16x32 bf16 layouts (verified m89/m91):
//   A-frag: lane l holds A[l&15][(l>>4)*8+e]; B-frag: B[(l>>4)*8+e][l&15]
//   C/D:    lane l holds C[(l>>4)*4+r][l&15]
// ---------------------------------------------------------------------------
__global__ __launch_bounds__(64) void fused_gcn_kernel(
    const float* __restrict__ A,             // [NNODES][NSRC] f32
    const unsigned short* __restrict__ supT, // [DIN][NSRC] bf16 bits
    const float* __restrict__ Wd,            // dense0_w [DIN][DIN] f32
    float* __restrict__ out) {               // [NNODES][DIN] f32
  const int lane = threadIdx.x & 63;
  const int r16 = lane & 15;
  const int g = lane >> 4;
  const int rowBase = blockIdx.x * 32;

  __shared__ float Abuf[2][32 * 64];            // 16 KB
  __shared__ unsigned short Bbuf[2][128 * 64];  // 32 KB
  __shared__ unsigned short act[32][136];       // 8.5 KB

  f32x4 acc[2][8];
#pragma unroll
  for (int m = 0; m < 2; ++m)
#pragma unroll
    for (int n = 0; n < 8; ++n) acc[m][n] = (f32x4){0.f, 0.f, 0.f, 0.f};

  // ---- staging: issue chunk -> LDS buffer `buf`, k-offset kc --------------
  // A: instr i2 covers rows i2*4..+3 (4 rows x 64 f32 = 1KB). lane: row =
  //    i2*4 + (lane>>4), slot = lane&15. source col = (slot ^ (row&15))*4.
  // B: instr i2 covers rows i2*8..+7 (8 rows x 64 bf16 = 1KB). lane: j =
  //    i2*8 + (lane>>3), slot = lane&7. source col = (slot ^ (j&7))*8.
#define STAGE(buf, kc)                                                        \
  {                                                                           \
    _Pragma("unroll") for (int i2 = 0; i2 < 8; ++i2) {                        \
      const int row = i2 * 4 + (lane >> 4);                                   \
      const int slt = lane & 15;                                              \
      const float* src = A + (size_t)(rowBase + row) * NSRC + (kc) +          \
                         ((slt ^ (row & 15)) << 2);                           \
      GLL16(src, &Abuf[buf][i2 * 256]);                                       \
    }                                                                         \
    _Pragma("unroll") for (int i2 = 0; i2 < 16; ++i2) {                       \
      const int j = i2 * 8 + (lane >> 3);                                     \
      const int slt = lane & 7;                                               \
      const unsigned short* src = supT + (size_t)j * NSRC + (kc) +            \
                                  ((slt ^ (j & 7)) << 3);                     \
      GLL16(src, &Bbuf[buf][i2 * 512]);                                       \
    }                                                                         \
  }

#define COMPUTE(buf)                                                          \
  {                                                                           \
    const float* ab = Abuf[buf];                                              \
    const unsigned short* bb = Bbuf[buf];                                     \
    _Pragma("unroll") for (int s = 0; s < 2; ++s) {                           \
      s16x8 afr[2];                                                           \
      _Pragma("unroll") for (int m = 0; m < 2; ++m) {                         \
        const int row = m * 16 + r16;                                         \
        const int t0 = s * 8 + g * 2;                                         \
        const float4 lo =                                                     \
            *(const float4*)&ab[row * 64 + ((t0 ^ r16) << 2)];                \
        const float4 hi =                                                     \
            *(const float4*)&ab[row * 64 + (((t0 + 1) ^ r16) << 2)];          \
        afr[m] = pack8(lo, hi);                                               \
      }                                                                       \
      _Pragma("unroll") for (int n = 0; n < 8; ++n) {                         \
        const int j = n * 16 + r16;                                           \
        const int bs = (s * 4 + g) ^ (r16 & 7);                               \
        const s16x8 b = *(const s16x8*)&bb[j * 64 + (bs << 3)];               \
        acc[0][n] =                                                           \
            __builtin_amdgcn_mfma_f32_16x16x32_bf16(afr[0], b, acc[0][n],     \
                                                    0, 0, 0);                 \
        acc[1][n] =                                                           \
            __builtin_amdgcn_mfma_f32_16x16x32_bf16(afr[1], b, acc[1][n],     \
                                                    0, 0, 0);                 \
      }                                                                       \
    }                                                                         \
  }

  // prologue: chunks 0,1 in flight (48 gll)
  STAGE(0, 0);
  STAGE(1, 64);
  // main loop: wait for chunk i (24 newer ops = chunk i+1 stay in flight),
  // compute, then refill the just-consumed buffer with chunk i+2.
  for (int i = 0; i < 31; ++i) {
    asm volatile("s_waitcnt vmcnt(24)" ::: "memory");
    COMPUTE(i & 1);
    if (i < 30) STAGE(i & 1, (i + 2) * 64);
  }
  asm volatile("s_waitcnt vmcnt(0)" ::: "memory");
  COMPUTE(1);  // chunk 31 -> buffer 31&1 = 1

  // ---- LeakyReLU + act tile to LDS (same as validated R2 code) ------------
#pragma unroll
  for (int m = 0; m < 2; ++m)
#pragma unroll
    for (int n = 0; n < 8; ++n)
#pragma unroll
      for (int r = 0; r < 4; ++r) {
        float v = acc[m][n][r];
        v = (v >= 0.f) ? v : 0.01f * v;
        act[m * 16 + g * 4 + r][n * 16 + r16] = f2bf(v);
      }
  __syncthreads();

  // ---- second GEMM: out[i][j] = sum_k act[i][k] * Wd[j][k] ----------------
  f32x4 acc2[2][8];
#pragma unroll
  for (int m = 0; m < 2; ++m)
#pragma unroll
    for (int n = 0; n < 8; ++n) acc2[m][n] = (f32x4){0.f, 0.f, 0.f, 0.f};

#pragma unroll
  for (int k2 = 0; k2 < 4; ++k2) {
    const int k = k2 * 32 + g * 8;
    const s16x8 a20 = *reinterpret_cast<const s16x8*>(&act[r16][k]);
    const s16x8 a21 = *reinterpret_cast<const s16x8*>(&act[16 + r16][k]);
#pragma unroll
    for (int n = 0; n < 8; ++n) {
      const s16x8 b2 = load_cvt8(Wd + (size_t)(n * 16 + r16) * DIN + k);
      acc2[0][n] = __builtin_amdgcn_mfma_f32_16x16x32_bf16(a20, b2, acc2[0][n], 0, 0, 0);
      acc2[1][n] = __builtin_amdgcn_mfma_f32_16x16x32_bf16(a21, b2, acc2[1][n], 0, 0, 0);
    }
  }

#pragma unroll
  for (int m = 0; m < 2; ++m)
#pragma unroll
    for (int n = 0; n < 8; ++n)
#pragma unroll
      for (int r = 0; r < 4; ++r)
        out[(size_t)(rowBase + m * 16 + g * 4 + r) * DIN + n * 16 + r16] =
            acc2[m][n][r];
}

// ---------------------------------------------------------------------------
extern "C" void kernel_launch(void* const* d_in, const int* in_sizes, int n_in,
                              void* d_out, int out_size, void* d_ws, size_t ws_size,
                              hipStream_t stream) {
  const float* x   = (const float*)d_in[0];   // [20000][128]
  const float* A   = (const float*)d_in[1];   // [20000][2048]
  const float* W   = (const float*)d_in[2];   // [128][128]
  const float* Wd  = (const float*)d_in[3];   // [128][128]
  const int*   src = (const int*)d_in[4];     // [2048]
  float* out = (float*)d_out;

  unsigned short* supT = (unsigned short*)d_ws;  // 128*2048*2 = 512 KB

  support_kernel<<<NSRC / 8, 128, 0, stream>>>(x, W, src, supT);
  fused_gcn_kernel<<<NNODES / 32, 64, 0, stream>>>(A, supT, Wd, out);
}